// Round 1
// 268.791 us; speedup vs baseline: 1.0150x; 1.0150x over previous
//
#include <hip/hip_runtime.h>
#include <math.h>

// PredictSpanSet: BS=32, BT=1024, DIM=512.
// score[b,t] = dot(sen_vecs[b,t,:], y_w[b,:]) + c_w[b]
//   where y_w[b,d] = sum_e W_w[e,d] * x[b,e],  c_w[b] = dot(bias_w, x[b]).
// Memory-bound on sen_vecs read (67 MB) + output write (134 MB).

#define BS 32
#define BT 1024
#define DIM 512
#define ECH 4            // e-chunks in k1 (parallelism for the tiny GEMM)
#define EC  (DIM / ECH)  // 128
#define NEG_MASK -1000000.0f
#define NEG_SPAN -1000.0f

typedef float f4 __attribute__((ext_vector_type(4)));

// ---------------------------------------------------------------------------
// K1: Yp[z][w][b][d] = sum_{e in chunk z} W_w[e][d]*x[b][e]
//     C[w][b]        = dot(bias_w, x[b])        (blockIdx.x==8, z==0 only)
// grid = (9, 3, 4), block = 256.  96 compute blocks, 128-iter e-loop:
// 4x the parallelism and 1/4 the dependent-load chain of the old version.
// ---------------------------------------------------------------------------
__global__ __launch_bounds__(256) void k1_proj(
    const float* __restrict__ x,
    const float* __restrict__ Wb, const float* __restrict__ bb,
    const float* __restrict__ Wi, const float* __restrict__ bi,
    const float* __restrict__ Wo, const float* __restrict__ bo,
    float* __restrict__ Yp, float* __restrict__ C)
{
    const int w = blockIdx.y;
    const int z = blockIdx.z;
    const float* __restrict__ W    = (w == 0) ? Wb : (w == 1) ? Wi : Wo;
    const float* __restrict__ bias = (w == 0) ? bb : (w == 1) ? bi : bo;
    const int tid = threadIdx.x;

    if (blockIdx.x == 8) {
        if (z != 0) return;
        const int v = tid >> 6, l = tid & 63;
        for (int b = v; b < BS; b += 4) {
            float acc = 0.f;
            for (int e = l; e < DIM; e += 64) acc += bias[e] * x[b * DIM + e];
            #pragma unroll
            for (int o = 32; o >= 1; o >>= 1) acc += __shfl_xor(acc, o);
            if (l == 0) C[w * BS + b] = acc;
        }
        return;
    }

    __shared__ float xs[BS * EC];            // 16 KB: X e-slice
    const int e0 = z * EC;
    for (int k = tid; k < BS * EC; k += 256) {
        const int b = k >> 7, e = k & (EC - 1);
        xs[k] = x[b * DIM + e0 + e];
    }
    __syncthreads();

    const int d0 = blockIdx.x * 64;
    const int dt = tid & 63, bg = tid >> 6;  // 64 d-lanes x 4 batch-groups
    const int d  = d0 + dt;

    float acc[8];
    #pragma unroll
    for (int i = 0; i < 8; i++) acc[i] = 0.f;
    for (int e = 0; e < EC; e++) {
        const float wv = W[(e0 + e) * DIM + d];   // coalesced across dt
        #pragma unroll
        for (int i = 0; i < 8; i++)
            acc[i] += wv * xs[(bg * 8 + i) * EC + e];  // LDS broadcast
    }
    #pragma unroll
    for (int i = 0; i < 8; i++)
        Yp[((z * 3 + w) * BS + bg * 8 + i) * DIM + d] = acc[i];
}

// ---------------------------------------------------------------------------
// K2a: per-row scores + lse. 8 rows per 256-thread block (2 per wave).
// Stages ys = sum_z Yp[z] (folds k1's partial reduction, L2-resident reads).
// grid = 32 * 128 = 4096, block = 256.
// ---------------------------------------------------------------------------
__global__ __launch_bounds__(256) void k2a_scores(
    const float* __restrict__ sv, const int* __restrict__ mask,
    const float* __restrict__ Yp, const float* __restrict__ C,
    float* __restrict__ SB, float* __restrict__ SI, float* __restrict__ SO,
    float* __restrict__ LSE)
{
    __shared__ float ys[3 * DIM];            // y_b | y_i | y_o for this batch
    const int blk = blockIdx.x;
    const int b   = blk >> 7;                // 128 blocks per batch
    const int t0  = (blk & 127) * 8;
    const int tid = threadIdx.x;

    for (int k = tid; k < 3 * DIM; k += 256) {
        const int w = k >> 9, d = k & (DIM - 1);
        float s = 0.f;
        #pragma unroll
        for (int zz = 0; zz < ECH; zz++)
            s += Yp[((zz * 3 + w) * BS + b) * DIM + d];
        ys[k] = s;
    }
    __syncthreads();

    const int v = tid >> 6, l = tid & 63;

    const f4* __restrict__ yb4 = (const f4*)(ys);
    const f4* __restrict__ yi4 = (const f4*)(ys + DIM);
    const f4* __restrict__ yo4 = (const f4*)(ys + 2 * DIM);

    // hoist y fragments to registers once; reuse across both rows
    const f4 yb1 = yb4[l], yb2 = yb4[64 + l];
    const f4 yi1 = yi4[l], yi2 = yi4[64 + l];
    const f4 yo1 = yo4[l], yo2 = yo4[64 + l];

    const int tA = t0 + v, tB = t0 + v + 4;
    const f4* __restrict__ svA = (const f4*)(sv + (size_t)(b * BT + tA) * DIM);
    const f4* __restrict__ svB = (const f4*)(sv + (size_t)(b * BT + tB) * DIM);

    // issue all 4 streaming loads up front (nontemporal: single-use data)
    const f4 a1 = __builtin_nontemporal_load(svA + l);
    const f4 a2 = __builtin_nontemporal_load(svA + 64 + l);
    const f4 b1 = __builtin_nontemporal_load(svB + l);
    const f4 b2 = __builtin_nontemporal_load(svB + 64 + l);

    #define DOT(p, q, y1, y2) \
        (p.x*y1.x + p.y*y1.y + p.z*y1.z + p.w*y1.w + \
         q.x*y2.x + q.y*y2.y + q.z*y2.z + q.w*y2.w)

    float rAB = DOT(a1, a2, yb1, yb2);
    float rAI = DOT(a1, a2, yi1, yi2);
    float rAO = DOT(a1, a2, yo1, yo2);
    float rBB = DOT(b1, b2, yb1, yb2);
    float rBI = DOT(b1, b2, yi1, yi2);
    float rBO = DOT(b1, b2, yo1, yo2);
    #undef DOT

    #pragma unroll
    for (int o = 32; o >= 1; o >>= 1) {
        rAB += __shfl_xor(rAB, o);
        rAI += __shfl_xor(rAI, o);
        rAO += __shfl_xor(rAO, o);
        rBB += __shfl_xor(rBB, o);
        rBI += __shfl_xor(rBI, o);
        rBO += __shfl_xor(rBO, o);
    }

    if (l == 0) {
        const float cb = C[0 * BS + b];
        const float ci = C[1 * BS + b];
        const float co = C[2 * BS + b];
        #pragma unroll
        for (int r = 0; r < 2; r++) {
            const int t = r ? tB : tA;
            float sb = (r ? rBB : rAB) + cb;
            float si = (r ? rBI : rAI) + ci;
            float so = (r ? rBO : rAO) + co;
            if (mask[b * BT + t] == 0) { sb = NEG_MASK; si = NEG_MASK; so = 0.f; }
            const float m   = fmaxf(sb, fmaxf(si, so));
            const float lse = m + logf(expf(sb - m) + expf(si - m) + expf(so - m));
            const int idx = b * BT + t;
            SB[idx] = sb; SI[idx] = si; SO[idx] = so; LSE[idx] = lse;
        }
    }
}

// ---------------------------------------------------------------------------
// K2b: per-batch block scan of lse and si; emit A[b,t], B[b,t].
// grid = 32, block = 1024
// ---------------------------------------------------------------------------
__global__ __launch_bounds__(1024) void k2b_scan(
    const float* __restrict__ SB, const float* __restrict__ SI,
    const float* __restrict__ SO, const float* __restrict__ LSE,
    float* __restrict__ A, float* __restrict__ Bv)
{
    __shared__ float sL[BT], sS[BT];
    const int b = blockIdx.x, t = threadIdx.x;
    const float l0 = LSE[b * BT + t];
    const float s0 = SI[b * BT + t];
    sL[t] = l0; sS[t] = s0;
    __syncthreads();

    for (int off = 1; off < BT; off <<= 1) {    // Hillis–Steele inclusive scan
        float a = 0.f, c = 0.f;
        if (t >= off) { a = sL[t - off]; c = sS[t - off]; }
        __syncthreads();
        if (t >= off) { sL[t] += a; sS[t] += c; }
        __syncthreads();
    }

    const float total = sL[BT - 1];             // full = sum of all lse
    const float pl = sL[t] - l0;                // exclusive prefix of lse
    const float ps = sS[t] - s0;                // exclusive prefix of si
    A [b * BT + t] = SB[b * BT + t] + pl - ps - total;
    Bv[b * BT + t] = ps + (total - sL[t]) + SO[b * BT + t];
}

// ---------------------------------------------------------------------------
// K3: out[b,i,j] = (j>=i) ? A[b,i]+B[b,j] : NEG_SPAN — nontemporal f4 stream.
// grid = 32768, block = 256  (one float4 per thread; one block = one i-row)
// ---------------------------------------------------------------------------
__global__ __launch_bounds__(256) void k3_span(
    const float* __restrict__ A, const float* __restrict__ Bv,
    f4* __restrict__ out)
{
    const int idx = blockIdx.x * 256 + threadIdx.x;  // 8,388,608 f4 slots
    const int b  = idx >> 18;
    const int r  = idx & 0x3FFFF;
    const int i  = r >> 8;
    const int j4 = r & 255;

    const float a = A[b * BT + i];                    // wave-uniform
    const f4 bb4 = ((const f4*)(Bv + b * BT))[j4];    // L2-hot, keep cached
    const int j = j4 * 4;
    f4 o;
    o.x = (j     >= i) ? a + bb4.x : NEG_SPAN;
    o.y = (j + 1 >= i) ? a + bb4.y : NEG_SPAN;
    o.z = (j + 2 >= i) ? a + bb4.z : NEG_SPAN;
    o.w = (j + 3 >= i) ? a + bb4.w : NEG_SPAN;
    __builtin_nontemporal_store(o, out + idx);        // 134 MB pure stream
}

// ---------------------------------------------------------------------------
extern "C" void kernel_launch(void* const* d_in, const int* in_sizes, int n_in,
                              void* d_out, int out_size, void* d_ws, size_t ws_size,
                              hipStream_t stream) {
    const float* x   = (const float*)d_in[0];
    const float* sv  = (const float*)d_in[1];
    const int*   msk = (const int*)  d_in[2];
    const float* Wb  = (const float*)d_in[3];
    const float* bb  = (const float*)d_in[4];
    const float* Wi  = (const float*)d_in[5];
    const float* bi  = (const float*)d_in[6];
    const float* Wo  = (const float*)d_in[7];
    const float* bo  = (const float*)d_in[8];

    float* ws = (float*)d_ws;
    // workspace layout (floats): total ~394k floats ≈ 1.5 MB
    float* Yp  = ws;                         // ECH*3*32*512 = 196608
    float* C   = ws + ECH * 3 * BS * DIM;    // 96 (padded to 512)
    float* SB  = C + 512;                    // 32*1024 each from here on
    float* SI  = SB + BS * BT;
    float* SO  = SI + BS * BT;
    float* LSE = SO + BS * BT;
    float* A   = LSE + BS * BT;
    float* Bv  = A + BS * BT;

    k1_proj   <<<dim3(9, 3, ECH), 256, 0, stream>>>(x, Wb, bb, Wi, bi, Wo, bo, Yp, C);
    k2a_scores<<<BS * 128, 256, 0, stream>>>(sv, msk, Yp, C, SB, SI, SO, LSE);
    k2b_scan  <<<BS, 1024, 0, stream>>>(SB, SI, SO, LSE, A, Bv);
    k3_span   <<<32768, 256, 0, stream>>>(A, Bv, (f4*)d_out);
}

// Round 2
// 265.167 us; speedup vs baseline: 1.0289x; 1.0137x over previous
//
#include <hip/hip_runtime.h>
#include <math.h>

// PredictSpanSet: BS=32, BT=1024, DIM=512.
// score[b,t] = dot(sen_vecs[b,t,:], y_w[b,:]) + c_w[b]
//   where y_w[b,d] = sum_e W_w[e,d] * x[b,e],  c_w[b] = dot(bias_w, x[b]).
// Memory-bound on sen_vecs read (67 MB) + output write (134 MB).

#define BS 32
#define BT 1024
#define DIM 512
#define ECH 4            // e-chunks in k1 (parallelism for the tiny GEMM)
#define EC  (DIM / ECH)  // 128
#define NEG_MASK -1000000.0f
#define NEG_SPAN -1000.0f

typedef float f4 __attribute__((ext_vector_type(4)));

// ---------------------------------------------------------------------------
// K1: Yp[z][w][b][d] = sum_{e in chunk z} W_w[e][d]*x[b][e]
//     C[w][b]        = dot(bias_w, x[b])        (blockIdx.x==8, z==0 only)
// grid = (9, 3, 4), block = 256.
// ---------------------------------------------------------------------------
__global__ __launch_bounds__(256) void k1_proj(
    const float* __restrict__ x,
    const float* __restrict__ Wb, const float* __restrict__ bb,
    const float* __restrict__ Wi, const float* __restrict__ bi,
    const float* __restrict__ Wo, const float* __restrict__ bo,
    float* __restrict__ Yp, float* __restrict__ C)
{
    const int w = blockIdx.y;
    const int z = blockIdx.z;
    const float* __restrict__ W    = (w == 0) ? Wb : (w == 1) ? Wi : Wo;
    const float* __restrict__ bias = (w == 0) ? bb : (w == 1) ? bi : bo;
    const int tid = threadIdx.x;

    if (blockIdx.x == 8) {
        if (z != 0) return;
        const int v = tid >> 6, l = tid & 63;
        for (int b = v; b < BS; b += 4) {
            float acc = 0.f;
            for (int e = l; e < DIM; e += 64) acc += bias[e] * x[b * DIM + e];
            #pragma unroll
            for (int o = 32; o >= 1; o >>= 1) acc += __shfl_xor(acc, o);
            if (l == 0) C[w * BS + b] = acc;
        }
        return;
    }

    __shared__ float xs[BS * EC];            // 16 KB: X e-slice
    const int e0 = z * EC;
    for (int k = tid; k < BS * EC; k += 256) {
        const int b = k >> 7, e = k & (EC - 1);
        xs[k] = x[b * DIM + e0 + e];
    }
    __syncthreads();

    const int d0 = blockIdx.x * 64;
    const int dt = tid & 63, bg = tid >> 6;  // 64 d-lanes x 4 batch-groups
    const int d  = d0 + dt;

    float acc[8];
    #pragma unroll
    for (int i = 0; i < 8; i++) acc[i] = 0.f;
    for (int e = 0; e < EC; e++) {
        const float wv = W[(e0 + e) * DIM + d];   // coalesced across dt
        #pragma unroll
        for (int i = 0; i < 8; i++)
            acc[i] += wv * xs[(bg * 8 + i) * EC + e];  // LDS broadcast
    }
    #pragma unroll
    for (int i = 0; i < 8; i++)
        Yp[((z * 3 + w) * BS + bg * 8 + i) * DIM + d] = acc[i];
}

// ---------------------------------------------------------------------------
// K2a: per-row scores + lse. 16 rows per 256-thread block (4 per wave):
// 8 nontemporal 16B loads in flight per lane before the reduce.
// grid = 32 * 64 = 2048 blocks (= 8 blocks/CU, one full residency shot).
// ---------------------------------------------------------------------------
__global__ __launch_bounds__(256) void k2a_scores(
    const float* __restrict__ sv, const int* __restrict__ mask,
    const float* __restrict__ Yp, const float* __restrict__ C,
    float* __restrict__ SB, float* __restrict__ SI, float* __restrict__ SO,
    float* __restrict__ LSE)
{
    __shared__ float ys[3 * DIM];            // y_b | y_i | y_o for this batch
    const int blk = blockIdx.x;
    const int b   = blk >> 6;                // 64 blocks per batch
    const int t0  = (blk & 63) * 16;
    const int tid = threadIdx.x;

    for (int k = tid; k < 3 * DIM; k += 256) {
        const int w = k >> 9, d = k & (DIM - 1);
        float s = 0.f;
        #pragma unroll
        for (int zz = 0; zz < ECH; zz++)
            s += Yp[((zz * 3 + w) * BS + b) * DIM + d];
        ys[k] = s;
    }
    __syncthreads();

    const int v = tid >> 6, l = tid & 63;

    const f4* __restrict__ yb4 = (const f4*)(ys);
    const f4* __restrict__ yi4 = (const f4*)(ys + DIM);
    const f4* __restrict__ yo4 = (const f4*)(ys + 2 * DIM);

    const f4 yb1 = yb4[l], yb2 = yb4[64 + l];
    const f4 yi1 = yi4[l], yi2 = yi4[64 + l];
    const f4 yo1 = yo4[l], yo2 = yo4[64 + l];

    // 4 rows per wave: t = t0 + v + 4*r.  Issue all 8 streaming loads first.
    f4 s1[4], s2[4];
    #pragma unroll
    for (int r = 0; r < 4; r++) {
        const f4* __restrict__ p =
            (const f4*)(sv + (size_t)(b * BT + t0 + v + 4 * r) * DIM);
        s1[r] = __builtin_nontemporal_load(p + l);
        s2[r] = __builtin_nontemporal_load(p + 64 + l);
    }

    #define DOT(p, q, y1, y2) \
        (p.x*y1.x + p.y*y1.y + p.z*y1.z + p.w*y1.w + \
         q.x*y2.x + q.y*y2.y + q.z*y2.z + q.w*y2.w)

    float rB[4], rI[4], rO[4];
    #pragma unroll
    for (int r = 0; r < 4; r++) {
        rB[r] = DOT(s1[r], s2[r], yb1, yb2);
        rI[r] = DOT(s1[r], s2[r], yi1, yi2);
        rO[r] = DOT(s1[r], s2[r], yo1, yo2);
    }
    #undef DOT

    #pragma unroll
    for (int o = 32; o >= 1; o >>= 1) {
        #pragma unroll
        for (int r = 0; r < 4; r++) {
            rB[r] += __shfl_xor(rB[r], o);
            rI[r] += __shfl_xor(rI[r], o);
            rO[r] += __shfl_xor(rO[r], o);
        }
    }

    if (l == 0) {
        const float cb = C[0 * BS + b];
        const float ci = C[1 * BS + b];
        const float co = C[2 * BS + b];
        #pragma unroll
        for (int r = 0; r < 4; r++) {
            const int t = t0 + v + 4 * r;
            float sb = rB[r] + cb;
            float si = rI[r] + ci;
            float so = rO[r] + co;
            if (mask[b * BT + t] == 0) { sb = NEG_MASK; si = NEG_MASK; so = 0.f; }
            const float m   = fmaxf(sb, fmaxf(si, so));
            const float lse = m + logf(expf(sb - m) + expf(si - m) + expf(so - m));
            const int idx = b * BT + t;
            SB[idx] = sb; SI[idx] = si; SO[idx] = so; LSE[idx] = lse;
        }
    }
}

// ---------------------------------------------------------------------------
// K2b: per-batch scan of lse and si via wave shfl (Kogge-Stone) + one LDS
// hop for the 16 wave totals — 1 barrier instead of 20.
// grid = 32, block = 1024
// ---------------------------------------------------------------------------
__global__ __launch_bounds__(1024) void k2b_scan(
    const float* __restrict__ SB, const float* __restrict__ SI,
    const float* __restrict__ SO, const float* __restrict__ LSE,
    float* __restrict__ A, float* __restrict__ Bv)
{
    __shared__ float wL[16], wS[16];
    const int b = blockIdx.x, t = threadIdx.x;
    const int wv = t >> 6, l = t & 63;

    const float l0 = LSE[b * BT + t];
    const float s0 = SI[b * BT + t];

    // in-wave inclusive scan (Kogge-Stone over 64 lanes)
    float cl = l0, cs = s0;
    #pragma unroll
    for (int off = 1; off < 64; off <<= 1) {
        const float al = __shfl_up(cl, off);
        const float as = __shfl_up(cs, off);
        if (l >= off) { cl += al; cs += as; }
    }
    if (l == 63) { wL[wv] = cl; wS[wv] = cs; }
    __syncthreads();

    // per-thread: accumulate total and prefix-of-preceding-waves (LDS bcast)
    float basL = 0.f, basS = 0.f, totL = 0.f, totS = 0.f;
    #pragma unroll
    for (int w = 0; w < 16; w++) {
        const float a = wL[w], c = wS[w];
        totL += a; totS += c;
        if (w < wv) { basL += a; basS += c; }
    }

    const float incL = cl + basL;               // inclusive prefix of lse
    const float incS = cs + basS;               // inclusive prefix of si
    const float pl = incL - l0;                 // exclusive prefix of lse
    const float ps = incS - s0;                 // exclusive prefix of si
    A [b * BT + t] = SB[b * BT + t] + pl - ps - totL;
    Bv[b * BT + t] = ps + (totL - incL) + SO[b * BT + t];
}

// ---------------------------------------------------------------------------
// K3: out[b,i,j] = (j>=i) ? A[b,i]+B[b,j] : NEG_SPAN.
// One wave per output row: 4 coalesced nontemporal f4 stores per lane.
// grid = 8192, block = 256 (4 waves = 4 rows/block).
// ---------------------------------------------------------------------------
__global__ __launch_bounds__(256) void k3_span(
    const float* __restrict__ A, const float* __restrict__ Bv,
    f4* __restrict__ out)
{
    const int g = blockIdx.x * 4 + (threadIdx.x >> 6);  // global row, 0..32767
    const int l = threadIdx.x & 63;
    const int i = g & 1023;                             // row within batch

    const float a = A[g];                               // wave-uniform (A[b*BT+i] == A[g])
    const f4* __restrict__ bv = (const f4*)(Bv + (g & ~1023));  // batch row base
    f4* __restrict__ orow = out + ((size_t)g << 8);

    #pragma unroll
    for (int k = 0; k < 4; k++) {
        const int j4 = l + 64 * k;
        const f4 b4 = bv[j4];                           // L2-hot (4 KB/batch)
        const int j = j4 * 4;
        f4 o;
        o.x = (j     >= i) ? a + b4.x : NEG_SPAN;
        o.y = (j + 1 >= i) ? a + b4.y : NEG_SPAN;
        o.z = (j + 2 >= i) ? a + b4.z : NEG_SPAN;
        o.w = (j + 3 >= i) ? a + b4.w : NEG_SPAN;
        __builtin_nontemporal_store(o, orow + j4);      // 134 MB pure stream
    }
}

// ---------------------------------------------------------------------------
extern "C" void kernel_launch(void* const* d_in, const int* in_sizes, int n_in,
                              void* d_out, int out_size, void* d_ws, size_t ws_size,
                              hipStream_t stream) {
    const float* x   = (const float*)d_in[0];
    const float* sv  = (const float*)d_in[1];
    const int*   msk = (const int*)  d_in[2];
    const float* Wb  = (const float*)d_in[3];
    const float* bb  = (const float*)d_in[4];
    const float* Wi  = (const float*)d_in[5];
    const float* bi  = (const float*)d_in[6];
    const float* Wo  = (const float*)d_in[7];
    const float* bo  = (const float*)d_in[8];

    float* ws = (float*)d_ws;
    float* Yp  = ws;                         // ECH*3*32*512 = 196608 floats
    float* C   = ws + ECH * 3 * BS * DIM;    // 96 (padded to 512)
    float* SB  = C + 512;
    float* SI  = SB + BS * BT;
    float* SO  = SI + BS * BT;
    float* LSE = SO + BS * BT;
    float* A   = LSE + BS * BT;
    float* Bv  = A + BS * BT;

    k1_proj   <<<dim3(9, 3, ECH), 256, 0, stream>>>(x, Wb, bb, Wi, bi, Wo, bo, Yp, C);
    k2a_scores<<<BS * 64, 256, 0, stream>>>(sv, msk, Yp, C, SB, SI, SO, LSE);
    k2b_scan  <<<BS, 1024, 0, stream>>>(SB, SI, SO, LSE, A, Bv);
    k3_span   <<<8192, 256, 0, stream>>>(A, Bv, (f4*)d_out);
}